// Round 7
// baseline (136.496 us; speedup 1.0000x reference)
//
#include <hip/hip_runtime.h>

#define BATCH 32
#define H 512
#define W 512
#define PADR 4
#define WIN 9
#define SEG 16                      // output rows per block
#define COLS 8                      // output columns per lane
#define NT 64                       // ONE wave per block: 64 x 8 = 512 cols
#define NSTEP (SEG + WIN - 1)       // 24 row-steps, fully unrolled
// final scalar = sum over pixels of ((1-cc1)+(1-cc2)) * 0.5 / (B*H*W)
#define SCALE (0.5f / 8388608.0f)

typedef float v4f __attribute__((ext_vector_type(4)));

// Round 7: R6's barrier-free DPP structure (HW-verified correct) minus the
// register blow-up.  The raw-pixel ring (216 regs -> spill at the 256 cap)
// is replaced by RE-LOADING the row that leaves the vertical window from
// L2 (it was fetched 9 steps ago; 54 KB working set << 4 MB L2).  Emit is
// split into two 4-column halves (S: 64 -> 32 regs).  State ~195 regs.

__device__ __forceinline__ float from_left(float v) {   // lane i <- i-1; lane 0 <- 0
    return __builtin_bit_cast(float, __builtin_amdgcn_update_dpp(
        0, __builtin_bit_cast(int, v), 0x138, 0xF, 0xF, true)); // wave_shr:1
}
__device__ __forceinline__ float from_right(float v) {  // lane i <- i+1; lane 63 <- 0
    return __builtin_bit_cast(float, __builtin_amdgcn_update_dpp(
        0, __builtin_bit_cast(int, v), 0x130, 0xF, 0xF, true)); // wave_shl:1
}

// Window sums, columns 0..3 of this lane (needs left-lane suffixes).
#define EMITQ_LO(qi) do {                                     \
    const float p4 = (V[qi][0] + V[qi][1]) + (V[qi][2] + V[qi][3]); \
    const float p5 = p4 + V[qi][4];                           \
    const float p6 = p5 + V[qi][5];                           \
    const float p7 = p6 + V[qi][6];                           \
    const float T  = p7 + V[qi][7];                           \
    const float l0 = from_left(T - p4);                       \
    const float l1 = from_left(T - p5);                       \
    const float l2 = from_left(T - p6);                       \
    const float l3 = from_left(V[qi][7]);  /* T - p7 */       \
    S[qi][0] = l0 + p5;                                       \
    S[qi][1] = l1 + p6;                                       \
    S[qi][2] = l2 + p7;                                       \
    S[qi][3] = l3 + T;                                        \
} while (0)

// Window sums, columns 4..7 of this lane (needs right-lane prefixes).
#define EMITQ_HI(qi) do {                                     \
    const float p1 = V[qi][0];                                \
    const float p2 = p1 + V[qi][1];                           \
    const float p3 = p2 + V[qi][2];                           \
    const float p4 = p3 + V[qi][3];                           \
    const float T  = p4 + ((V[qi][4] + V[qi][5]) + (V[qi][6] + V[qi][7])); \
    const float r4 = from_right(p1);                          \
    const float r5 = from_right(p2);                          \
    const float r6 = from_right(p3);                          \
    const float r7 = from_right(p4);                          \
    S[qi][0] = T + r4;                                        \
    S[qi][1] = (T - p1) + r5;                                 \
    S[qi][2] = (T - p2) + r6;                                 \
    S[qi][3] = (T - p3) + r7;                                 \
} while (0)

// NCC epilogue over the 4 columns currently in S.
#define EPILOG4() do {                                        \
    _Pragma("unroll")                                         \
    for (int c = 0; c < 4; ++c) {                             \
        const float sA = S[0][c], sC = S[1][c], sF = S[2][c]; \
        const float u1 = sA * inv_n;                          \
        const float u2 = sC * inv_n;                          \
        const float uf = sF * inv_n;                          \
        const float cross1 = fmaf(-sA, uf, S[6][c]);          \
        const float var1   = fmaf(-sA, u1, S[3][c]);          \
        const float varf   = fmaf(-sF, uf, S[5][c]);          \
        const float cross2 = fmaf(-sC, uf, S[7][c]);          \
        const float var2   = fmaf(-sC, u2, S[4][c]);          \
        const float d1 = fmaf(var1, varf, 1e-5f);             \
        const float d2 = fmaf(var2, varf, 1e-5f);             \
        const float inv = __builtin_amdgcn_rcpf(d1 * d2);     \
        float num = cross1 * cross1 * d2;                     \
        num = fmaf(cross2 * cross2, d1, num);                 \
        lsum += fmaf(-num, inv, 2.0f);                        \
    }                                                         \
} while (0)

__global__ __launch_bounds__(NT, 1) void ncc_loss_kernel(
    const float* __restrict__ g1, const float* __restrict__ g2,
    const float* __restrict__ gf, float* __restrict__ out)
{
    const int t  = threadIdx.x;              // 0..63 (one wave)
    const int x0 = t * COLS;                 // 0,8,...,504
    const int y0 = blockIdx.y * SEG;
    const int b  = blockIdx.z;
    const size_t base = (size_t)b * (size_t)(H * W);
    const int voff = x0 * 4;

    // Incoming row: double-buffered [parity][image][half].
    v4f nbuf[2][3][2];
    // Outgoing row (re-loaded from L2): SINGLE buffer, issued one step
    // ahead right after the current step's V-update consumed it; the emit
    // phase (~700 cyc) covers the ~200-cyc L2 latency.
    v4f obuf[3][2];

    auto issue6 = [&](int yr, v4f (*dst)[2]) {
        const int rec = ((unsigned)yr < (unsigned)H) ? (W * 4) : 0; // OOB row -> 0
        const int yc  = yr < 0 ? 0 : (yr >= H ? H - 1 : yr);        // safe base
        const size_t roff = base + (size_t)yc * W;                  // block-uniform
        __amdgpu_buffer_rsrc_t r1 = __builtin_amdgcn_make_buffer_rsrc(
            (void*)(g1 + roff), (short)0, rec, 0x00020000);
        __amdgpu_buffer_rsrc_t r2 = __builtin_amdgcn_make_buffer_rsrc(
            (void*)(g2 + roff), (short)0, rec, 0x00020000);
        __amdgpu_buffer_rsrc_t rf = __builtin_amdgcn_make_buffer_rsrc(
            (void*)(gf + roff), (short)0, rec, 0x00020000);
        dst[0][0] = __builtin_bit_cast(v4f,
            __builtin_amdgcn_raw_buffer_load_b128(r1, voff, 0, 0));
        dst[0][1] = __builtin_bit_cast(v4f,
            __builtin_amdgcn_raw_buffer_load_b128(r1, voff + 16, 0, 0));
        dst[1][0] = __builtin_bit_cast(v4f,
            __builtin_amdgcn_raw_buffer_load_b128(r2, voff, 0, 0));
        dst[1][1] = __builtin_bit_cast(v4f,
            __builtin_amdgcn_raw_buffer_load_b128(r2, voff + 16, 0, 0));
        dst[2][0] = __builtin_bit_cast(v4f,
            __builtin_amdgcn_raw_buffer_load_b128(rf, voff, 0, 0));
        dst[2][1] = __builtin_bit_cast(v4f,
            __builtin_amdgcn_raw_buffer_load_b128(rf, voff + 16, 0, 0));
    };

    // Vertical running box-sums: q = {A, C, F, AA, CC, FF, AF, CF}.
    float V[8][COLS];
#pragma unroll
    for (int q = 0; q < 8; ++q)
#pragma unroll
        for (int c = 0; c < COLS; ++c) V[q][c] = 0.f;

    float lsum = 0.f;
    const float inv_n = 1.0f / 81.0f;

    issue6(y0 - PADR, nbuf[0]);              // prologue prefetch (step 0)

#pragma unroll
    for (int s = 0; s < NSTEP; ++s) {
        if (s + 1 < NSTEP) issue6(y0 - PADR + (s + 1), nbuf[(s + 1) & 1]);

        // vertical sliding update; first WIN steps have nothing to subtract
#pragma unroll
        for (int c = 0; c < COLS; ++c) {
            const float n1 = nbuf[s & 1][0][c >> 2][c & 3];
            const float n2 = nbuf[s & 1][1][c >> 2][c & 3];
            const float nf = nbuf[s & 1][2][c >> 2][c & 3];
            if (s >= WIN) {                  // compile-time
                const float o1 = obuf[0][c >> 2][c & 3];
                const float o2 = obuf[1][c >> 2][c & 3];
                const float of = obuf[2][c >> 2][c & 3];
                V[0][c] += n1 - o1;
                V[1][c] += n2 - o2;
                V[2][c] += nf - of;
                V[3][c] = fmaf(n1, n1, fmaf(-o1, o1, V[3][c]));
                V[4][c] = fmaf(n2, n2, fmaf(-o2, o2, V[4][c]));
                V[5][c] = fmaf(nf, nf, fmaf(-of, of, V[5][c]));
                V[6][c] = fmaf(n1, nf, fmaf(-o1, of, V[6][c]));
                V[7][c] = fmaf(n2, nf, fmaf(-o2, of, V[7][c]));
            } else {
                V[0][c] += n1;
                V[1][c] += n2;
                V[2][c] += nf;
                V[3][c] = fmaf(n1, n1, V[3][c]);
                V[4][c] = fmaf(n2, n2, V[4][c]);
                V[5][c] = fmaf(nf, nf, V[5][c]);
                V[6][c] = fmaf(n1, nf, V[6][c]);
                V[7][c] = fmaf(n2, nf, V[7][c]);
            }
        }

        // issue next step's OUTGOING row (L2-hot re-load); obuf already
        // consumed above, emit below covers the latency
        if (s + 1 >= WIN && s + 1 < NSTEP)
            issue6(y0 - PADR + (s + 1) - WIN, obuf);

        if (s >= WIN - 1) {                  // emit output row y0 + s - 8
            float S[8][4];
            // columns 0..3 of each lane
            EMITQ_LO(0); EMITQ_LO(1); EMITQ_LO(2); EMITQ_LO(3);
            EMITQ_LO(4); EMITQ_LO(5); EMITQ_LO(6); EMITQ_LO(7);
            EPILOG4();
            // columns 4..7 of each lane
            EMITQ_HI(0); EMITQ_HI(1); EMITQ_HI(2); EMITQ_HI(3);
            EMITQ_HI(4); EMITQ_HI(5); EMITQ_HI(6); EMITQ_HI(7);
            EPILOG4();
        }
    }

    // single-wave reduction: shuffle only, one atomic per block, no LDS
#pragma unroll
    for (int offd = 32; offd > 0; offd >>= 1)
        lsum += __shfl_down(lsum, offd);
    if (t == 0) atomicAdd(out, lsum * SCALE);
}

extern "C" void kernel_launch(void* const* d_in, const int* in_sizes, int n_in,
                              void* d_out, int out_size, void* d_ws, size_t ws_size,
                              hipStream_t stream) {
    const float* img1 = (const float*)d_in[0];
    const float* img2 = (const float*)d_in[1];
    const float* fimg = (const float*)d_in[2];
    float* out = (float*)d_out;

    hipMemsetAsync(out, 0, sizeof(float), stream);  // d_out re-poisoned each call

    dim3 grid(1, H / SEG, BATCH);        // (1, 32, 32) = 1024 blocks, 1 wave each
    ncc_loss_kernel<<<grid, dim3(NT), 0, stream>>>(img1, img2, fimg, out);
}